// Round 7
// baseline (278.959 us; speedup 1.0000x reference)
//
#include <hip/hip_runtime.h>
#include <hip/hip_bf16.h>
#include <stdint.h>

// ---------------- problem constants ----------------
#define NB   32
#define NC   256
#define NOC  256
#define HWD  56
#define NPIX 3136      // 56*56 = 14 * 224 exactly
#define PW   58        // padded row width
#define PPIX 3364      // 58*58
#define KTOT 2304      // 9 * 256
#define MOD  512       // fc1 out channels
#define GAPD 16

// workspace layout (bytes)
#define XBT_BYTES ((size_t)NB * PPIX * NC * 2)            // 55,115,776
#define WA_BYTES  ((size_t)NB * NOC * KTOT * 2)           // 37,748,736

typedef __bf16 bf16x8 __attribute__((ext_vector_type(8)));
typedef float  f32x4  __attribute__((ext_vector_type(4)));
typedef unsigned short u16x8 __attribute__((ext_vector_type(8)));

__device__ __forceinline__ unsigned short f2bf(float f) {
    union { float f; unsigned int u; } v; v.f = f;
    unsigned int u = v.u;
    return (unsigned short)((u + 0x7FFFu + ((u >> 16) & 1u)) >> 16);
}

// ---------------- P1: SE network (one block, 512 threads) ----------------
__global__ void se_kernel(const float* __restrict__ gap,
                          const float* __restrict__ rw, const float* __restrict__ rb,
                          const float* __restrict__ f1w, float* __restrict__ a2) {
    __shared__ float sgap[NB * NC];
    __shared__ float sg[NB * GAPD];
    int t = threadIdx.x; // 0..511
    #pragma unroll
    for (int i = 0; i < 16; ++i) sgap[i * 512 + t] = gap[i * 512 + t];
    __syncthreads();
    {
        int b = t >> 4, tt = t & 15;
        float s = rb[tt];
        for (int c = 0; c < NC; ++c) s += sgap[b * NC + c] * rw[tt * NC + c];
        sg[b * GAPD + tt] = s;
    }
    __syncthreads();
    for (int i = 0; i < 32; ++i) {
        int o = i * 512 + t;
        int b = o >> 9, m = o & 511;
        float s = 0.f;
        #pragma unroll
        for (int tt = 0; tt < GAPD; ++tt) s += sg[b * GAPD + tt] * f1w[m * GAPD + tt];
        a2[o] = 1.0f / (1.0f + __expf(-s));
    }
}

// ---------------- P2: per-batch conv weights; one block per oc, loop over b ----------------
__global__ void wk_kernel(const float* __restrict__ a2,
                          const float* __restrict__ f2w, const float* __restrict__ f2b,
                          unsigned short* __restrict__ wa) {
    __shared__ float sw[KTOT];
    __shared__ float sbv[KTOT];
    __shared__ float sa[2 * NB];
    int oc = blockIdx.x, c = threadIdx.x;
    const float4* wsrc = (const float4*)(f2w + (size_t)oc * KTOT);
    const float4* bsrc = (const float4*)(f2b + (size_t)oc * KTOT);
    #pragma unroll
    for (int i = 0; i < 3; ++i) {
        int idx = i * 256 + c;
        if (idx < 576) {
            ((float4*)sw)[idx] = wsrc[idx];
            ((float4*)sbv)[idx] = bsrc[idx];
        }
    }
    if (c < 64) sa[c] = a2[(c >> 1) * MOD + 2 * oc + (c & 1)];
    __syncthreads();
    float w9[9], b9[9];
    #pragma unroll
    for (int s = 0; s < 9; ++s) { w9[s] = sw[c * 9 + s]; b9[s] = sbv[c * 9 + s]; }
    for (int b = 0; b < NB; ++b) {
        float a0 = sa[2 * b], a1 = sa[2 * b + 1];
        unsigned short* dst = wa + (size_t)(b * NOC + oc) * KTOT;
        #pragma unroll
        for (int s = 0; s < 9; ++s) {
            float a = ((c * 9 + s) >= 1152) ? a1 : a0;
            dst[s * NC + c] = f2bf(a * w9[s] + b9[s]);
        }
    }
}

// ---------------- P3: zero the halo of xbt ----------------
__global__ void halo_kernel(unsigned short* __restrict__ xbt) {
    int b = blockIdx.x, t = threadIdx.x;
    unsigned short* xb = xbt + (size_t)b * PPIX * NC;
    u16x8 z = {};
    for (int i = t; i < 3712; i += 256) {
        int r = (i >= 1856) ? 1 : 0;
        int c = i - r * 1856;
        int pix = r * (57 * 58) + (c >> 5);
        *(u16x8*)(xb + (size_t)pix * NC + (c & 31) * 8) = z;
    }
    for (int i = t; i < 3584; i += 256) {
        int row = 1 + (i >> 6);
        int side = (i >> 5) & 1;
        int pix = row * PW + side * 57;
        *(u16x8*)(xb + (size_t)pix * NC + (i & 31) * 8) = z;
    }
}

// ---------------- P4: x -> bf16 NHWC with halo, fused GAP partial sums ----------------
#define TSTR 59
__global__ void xpose_kernel(const float* __restrict__ x, unsigned short* __restrict__ xbt,
                             float* __restrict__ gap) {
    __shared__ unsigned short tile[NC * TSTR];
    int py = blockIdx.x, b = blockIdx.y, t = threadIdx.x;
    int wv = t >> 6, l = t & 63;
    const float* xs = x + (size_t)b * NC * NPIX + py * HWD;
    int q = l & 15;
    int rb4 = l >> 4;
    #pragma unroll
    for (int it = 0; it < 16; ++it) {
        int c = wv * 64 + it * 4 + rb4;
        if (q < 14) {
            float4 v = *(const float4*)(xs + (size_t)c * NPIX + q * 4);
            unsigned short* tr = tile + c * TSTR + q * 4;
            tr[0] = f2bf(v.x); tr[1] = f2bf(v.y); tr[2] = f2bf(v.z); tr[3] = f2bf(v.w);
        }
    }
    __syncthreads();
    {
        float s = 0.f;
        #pragma unroll
        for (int px = 0; px < 56; ++px) {
            union { unsigned int u; float f; } cv;
            cv.u = ((unsigned int)tile[t * TSTR + px]) << 16;
            s += cv.f;
        }
        atomicAdd(&gap[b * NC + t], s * (1.0f / NPIX));
    }
    int cch = t & 31, pg = t >> 5;
    for (int i = 0; i < 7; ++i) {
        int px = pg * 7 + i;
        u16x8 v;
        #pragma unroll
        for (int j = 0; j < 8; ++j) v[j] = tile[(cch * 8 + j) * TSTR + px];
        *(u16x8*)(xbt + ((size_t)b * PPIX + (size_t)(1 + py) * PW + 1 + px) * NC + cch * 8) = v;
    }
}

// ---------------- main GEMM: 128oc x 224px block, 4 waves (64x112), A direct-to-reg ----------------
// K = 2304 = 72 phases of BK=32. A-fragments load global->VGPR (reg dbuf, distance 2);
// only B goes through LDS: slice = [256 rows pad][32 k] = 16 KB, ring-4 = 64 KB ->
// 2 blocks/CU co-resident (8 waves/CU). 3136 = 14*224 -> zero pixel padding.
// Per phase per thread: 4 B-stage gload_lds + 4 A plain loads = 8 vmem -> vmcnt(8)
// steady (vmcnt(0) once at phase 0). R2-proven B swizzle (0 conflicts).

__global__ __launch_bounds__(256, 2) void conv_gemm(
    const unsigned short* __restrict__ wa,   // [32][256][2304] bf16
    const unsigned short* __restrict__ xbt,  // [32][3364][256] bf16 (padded NHWC)
    float* __restrict__ out)                 // [32][256][3136]
{
    __shared__ __attribute__((aligned(16))) char lds[4 * 16384];  // 64 KB

    // XCD swizzle: 896 blocks = 8 XCD * 112; 4 whole batches per XCD
    const int bid = blockIdx.x;
    const int wg  = (bid & 7) * 112 + (bid >> 3);
    const int b   = wg / 28;
    const int r28 = wg % 28;
    const int oh  = r28 / 14, nt = r28 % 14;

    const int t = threadIdx.x;
    const int w = t >> 6, l = t & 63;            // 4 waves
    const int wm = w >> 1, wn = w & 1;           // 2M x 2N, wave tile 64oc x 112px

    // ---- A: direct global pointers, one per m-frag ----
    // lane l: oc-row = (l&15), k-chunk = (l>>4)*8 within the K-tile
    const unsigned short* pA[4];
    #pragma unroll
    for (int m = 0; m < 4; ++m) {
        int row = oh * 128 + wm * 64 + m * 16 + (l & 15);
        pA[m] = wa + (size_t)(b * NOC + row) * KTOT + (l >> 4) * 8;
    }

    // ---- B staging sources (pre-swizzled): granule s = j*256 + t ----
    // row = s>>2 (0..255; rows 224+ are never read), phys chunk s&3,
    // stored logical chunk q = (s&3) ^ ((s>>3)&3)
    const unsigned short* xbB = xbt + (size_t)b * PPIX * NC;
    const unsigned short* pB[4];
    #pragma unroll
    for (int j = 0; j < 4; ++j) {
        int s = j * 256 + t;
        int row = s >> 2;
        int q = (s & 3) ^ ((s >> 3) & 3);
        int pg = nt * 224 + row;                 // <= 3167; maps inside halo, safe
        int py = pg / 56, px = pg - py * 56;
        pB[j] = xbB + (size_t)((py + 1) * PW + (px + 1)) * NC + q * 8;
    }

    // ---- B read-side lane constants (R2-proven, 0 conflicts) ----
    const int physq16 = (((l >> 4) ^ ((l >> 1) & 3)) << 4);
    const int arow = (l & 15) << 6;

    f32x4 acc[4][7] = {};
    bf16x8 aA[4], aB[4];

#define STAGE_B(KT)                                                              \
    do {                                                                         \
        const int kn_ = (KT);                                                    \
        const int s9_ = kn_ >> 3;                                                \
        const int dy_ = (s9_ >= 6) ? 2 : ((s9_ >= 3) ? 1 : 0);                   \
        const int dx_ = s9_ - dy_ * 3;                                           \
        const int bsh_ = ((dy_ - 1) * PW + (dx_ - 1)) * NC + (kn_ & 7) * 32;     \
        char* sb_ = lds + (kn_ & 3) * 16384;                                     \
        _Pragma("unroll")                                                        \
        for (int j = 0; j < 4; ++j)                                              \
            __builtin_amdgcn_global_load_lds(                                    \
                (const __attribute__((address_space(1))) void*)(pB[j] + bsh_),   \
                (__attribute__((address_space(3))) void*)(sb_ + j * 4096 + w * 1024), \
                16, 0, 0);                                                       \
    } while (0)

#define LOAD_A(KT, ASET)                                                         \
    do {                                                                         \
        _Pragma("unroll")                                                        \
        for (int m = 0; m < 4; ++m)                                              \
            ASET[m] = *(const bf16x8*)(pA[m] + (KT) * 32);                       \
    } while (0)

#define PHASE(P, ASET, DO_ISSUE, VM)                                             \
    do {                                                                         \
        asm volatile("s_waitcnt vmcnt(" VM ")" ::: "memory");                    \
        __builtin_amdgcn_s_barrier();                                            \
        __builtin_amdgcn_sched_barrier(0);                                       \
        if (DO_ISSUE) STAGE_B((P) + 2);                                          \
        const char* rb_ = lds + ((P) & 3) * 16384;                               \
        bf16x8 bfr_[7];                                                          \
        _Pragma("unroll")                                                        \
        for (int nf = 0; nf < 7; ++nf)                                           \
            bfr_[nf] = *(const bf16x8*)(rb_ + (wn * 7 + nf) * 1024 + arow + physq16); \
        asm volatile("s_waitcnt lgkmcnt(0)" ::: "memory");                       \
        __builtin_amdgcn_sched_barrier(0);                                       \
        __builtin_amdgcn_s_setprio(1);                                           \
        _Pragma("unroll")                                                        \
        for (int m = 0; m < 4; ++m)                                              \
            _Pragma("unroll")                                                    \
            for (int nf = 0; nf < 7; ++nf)                                       \
                acc[m][nf] = __builtin_amdgcn_mfma_f32_16x16x32_bf16(            \
                    ASET[m], bfr_[nf], acc[m][nf], 0, 0, 0);                     \
        __builtin_amdgcn_s_setprio(0);                                           \
        if (DO_ISSUE) LOAD_A((P) + 2, ASET);                                     \
    } while (0)

    // prologue: B(0), A(0), B(1), A(1)
    STAGE_B(0); LOAD_A(0, aA);
    STAGE_B(1); LOAD_A(1, aB);

    PHASE(0, aA, 1, "0");      // one-time full drain (prologue issue order safety)
    PHASE(1, aB, 1, "8");
    for (int p = 2; p < 70; p += 2) {
        PHASE(p, aA, 1, "8");
        PHASE(p + 1, aB, 1, "8");
    }
    PHASE(70, aA, 0, "8");
    PHASE(71, aB, 0, "0");

    // epilogue: D lane map col = l&15 (pixel), row = (l>>4)*4 + r (oc)
    const int ocb = oh * 128 + wm * 64 + ((l >> 4) << 2);
    const int pxb = nt * 224 + wn * 112 + (l & 15);
    #pragma unroll
    for (int i = 0; i < 4; ++i) {
        #pragma unroll
        for (int j = 0; j < 7; ++j) {
            float* o = out + ((size_t)(b * NOC + ocb + i * 16)) * NPIX + pxb + j * 16;
            o[0]        = acc[i][j][0];
            o[NPIX]     = acc[i][j][1];
            o[2 * NPIX] = acc[i][j][2];
            o[3 * NPIX] = acc[i][j][3];
        }
    }
#undef PHASE
#undef LOAD_A
#undef STAGE_B
}

extern "C" void kernel_launch(void* const* d_in, const int* in_sizes, int n_in,
                              void* d_out, int out_size, void* d_ws, size_t ws_size,
                              hipStream_t stream) {
    (void)in_sizes; (void)n_in; (void)out_size; (void)ws_size;
    const float* x   = (const float*)d_in[0];
    const float* rw  = (const float*)d_in[1];
    const float* rb  = (const float*)d_in[2];
    const float* f1w = (const float*)d_in[3];
    const float* f2w = (const float*)d_in[4];
    const float* f2b = (const float*)d_in[5];
    float* out = (float*)d_out;

    char* wsb = (char*)d_ws;
    unsigned short* xbt = (unsigned short*)wsb;
    unsigned short* wa  = (unsigned short*)(wsb + XBT_BYTES);
    float* gap = (float*)(wsb + XBT_BYTES + WA_BYTES);
    float* a2  = (float*)(wsb + XBT_BYTES + WA_BYTES + (size_t)NB * NC * 4);

    hipMemsetAsync(gap, 0, (size_t)NB * NC * 4, stream);
    halo_kernel<<<dim3(32), 256, 0, stream>>>(xbt);
    xpose_kernel<<<dim3(56, 32), 256, 0, stream>>>(x, xbt, gap);
    se_kernel<<<dim3(1), 512, 0, stream>>>(gap, rw, rb, f1w, a2);
    wk_kernel<<<dim3(256), 256, 0, stream>>>(a2, f2w, f2b, wa);
    conv_gemm<<<dim3(896), 256, 0, stream>>>(wa, xbt, out);
}

// Round 8
// 206.743 us; speedup vs baseline: 1.3493x; 1.3493x over previous
//
#include <hip/hip_runtime.h>
#include <hip/hip_bf16.h>
#include <stdint.h>

// ---------------- problem constants ----------------
#define NB   32
#define NC   256
#define NOC  256
#define HWD  56
#define NPIX 3136      // 56*56
#define PW   58        // padded row width
#define PPIX 3364      // 58*58
#define KTOT 2304      // 9 * 256
#define MOD  512       // fc1 out channels
#define GAPD 16

// workspace layout (bytes)
#define XBT_BYTES ((size_t)NB * PPIX * NC * 2)            // 55,115,776
#define WA_BYTES  ((size_t)NB * NOC * KTOT * 2)           // 37,748,736

typedef __bf16 bf16x8 __attribute__((ext_vector_type(8)));
typedef float  f32x4  __attribute__((ext_vector_type(4)));
typedef unsigned short u16x8 __attribute__((ext_vector_type(8)));

__device__ __forceinline__ unsigned short f2bf(float f) {
    union { float f; unsigned int u; } v; v.f = f;
    unsigned int u = v.u;
    return (unsigned short)((u + 0x7FFFu + ((u >> 16) & 1u)) >> 16);
}

// ---------------- P1: SE network (one block, 512 threads) ----------------
__global__ void se_kernel(const float* __restrict__ gap,
                          const float* __restrict__ rw, const float* __restrict__ rb,
                          const float* __restrict__ f1w, float* __restrict__ a2) {
    __shared__ float sgap[NB * NC];
    __shared__ float sg[NB * GAPD];
    int t = threadIdx.x; // 0..511
    #pragma unroll
    for (int i = 0; i < 16; ++i) sgap[i * 512 + t] = gap[i * 512 + t];
    __syncthreads();
    {
        int b = t >> 4, tt = t & 15;
        float s = rb[tt];
        for (int c = 0; c < NC; ++c) s += sgap[b * NC + c] * rw[tt * NC + c];
        sg[b * GAPD + tt] = s;
    }
    __syncthreads();
    for (int i = 0; i < 32; ++i) {
        int o = i * 512 + t;
        int b = o >> 9, m = o & 511;
        float s = 0.f;
        #pragma unroll
        for (int tt = 0; tt < GAPD; ++tt) s += sg[b * GAPD + tt] * f1w[m * GAPD + tt];
        a2[o] = 1.0f / (1.0f + __expf(-s));
    }
}

// ---------------- P2: per-batch conv weights; one block per oc, loop over b ----------------
__global__ void wk_kernel(const float* __restrict__ a2,
                          const float* __restrict__ f2w, const float* __restrict__ f2b,
                          unsigned short* __restrict__ wa) {
    __shared__ float sw[KTOT];
    __shared__ float sbv[KTOT];
    __shared__ float sa[2 * NB];
    int oc = blockIdx.x, c = threadIdx.x;
    const float4* wsrc = (const float4*)(f2w + (size_t)oc * KTOT);
    const float4* bsrc = (const float4*)(f2b + (size_t)oc * KTOT);
    #pragma unroll
    for (int i = 0; i < 3; ++i) {
        int idx = i * 256 + c;
        if (idx < 576) {
            ((float4*)sw)[idx] = wsrc[idx];
            ((float4*)sbv)[idx] = bsrc[idx];
        }
    }
    if (c < 64) sa[c] = a2[(c >> 1) * MOD + 2 * oc + (c & 1)];
    __syncthreads();
    float w9[9], b9[9];
    #pragma unroll
    for (int s = 0; s < 9; ++s) { w9[s] = sw[c * 9 + s]; b9[s] = sbv[c * 9 + s]; }
    for (int b = 0; b < NB; ++b) {
        float a0 = sa[2 * b], a1 = sa[2 * b + 1];
        unsigned short* dst = wa + (size_t)(b * NOC + oc) * KTOT;
        #pragma unroll
        for (int s = 0; s < 9; ++s) {
            float a = ((c * 9 + s) >= 1152) ? a1 : a0;
            dst[s * NC + c] = f2bf(a * w9[s] + b9[s]);
        }
    }
}

// ---------------- P3: zero the halo of xbt ----------------
__global__ void halo_kernel(unsigned short* __restrict__ xbt) {
    int b = blockIdx.x, t = threadIdx.x;
    unsigned short* xb = xbt + (size_t)b * PPIX * NC;
    u16x8 z = {};
    for (int i = t; i < 3712; i += 256) {
        int r = (i >= 1856) ? 1 : 0;
        int c = i - r * 1856;
        int pix = r * (57 * 58) + (c >> 5);
        *(u16x8*)(xb + (size_t)pix * NC + (c & 31) * 8) = z;
    }
    for (int i = t; i < 3584; i += 256) {
        int row = 1 + (i >> 6);
        int side = (i >> 5) & 1;
        int pix = row * PW + side * 57;
        *(u16x8*)(xb + (size_t)pix * NC + (i & 31) * 8) = z;
    }
}

// ---------------- P4: x -> bf16 NHWC with halo, fused GAP partial sums ----------------
#define TSTR 59
__global__ void xpose_kernel(const float* __restrict__ x, unsigned short* __restrict__ xbt,
                             float* __restrict__ gap) {
    __shared__ unsigned short tile[NC * TSTR];
    int py = blockIdx.x, b = blockIdx.y, t = threadIdx.x;
    int wv = t >> 6, l = t & 63;
    const float* xs = x + (size_t)b * NC * NPIX + py * HWD;
    int q = l & 15;
    int rb4 = l >> 4;
    #pragma unroll
    for (int it = 0; it < 16; ++it) {
        int c = wv * 64 + it * 4 + rb4;
        if (q < 14) {
            float4 v = *(const float4*)(xs + (size_t)c * NPIX + q * 4);
            unsigned short* tr = tile + c * TSTR + q * 4;
            tr[0] = f2bf(v.x); tr[1] = f2bf(v.y); tr[2] = f2bf(v.z); tr[3] = f2bf(v.w);
        }
    }
    __syncthreads();
    {
        float s = 0.f;
        #pragma unroll
        for (int px = 0; px < 56; ++px) {
            union { unsigned int u; float f; } cv;
            cv.u = ((unsigned int)tile[t * TSTR + px]) << 16;
            s += cv.f;
        }
        atomicAdd(&gap[b * NC + t], s * (1.0f / NPIX));
    }
    int cch = t & 31, pg = t >> 5;
    for (int i = 0; i < 7; ++i) {
        int px = pg * 7 + i;
        u16x8 v;
        #pragma unroll
        for (int j = 0; j < 8; ++j) v[j] = tile[(cch * 8 + j) * TSTR + px];
        *(u16x8*)(xbt + ((size_t)b * PPIX + (size_t)(1 + py) * PW + 1 + px) * NC + cch * 8) = v;
    }
}

// ---------------- main GEMM: 256x256 tile, 8 waves, BK=64, 4 fine phases/K-tile ----------------
// K = 2304 = 36 K-tiles of 64. LDS dbuf: per buffer {A-k0 16K, A-k1 16K, B-k0 16K, B-k1 16K}
// = 64 KB, x2 = 128 KB. Per phase: [vmcnt] barrier; ds_read(4-8 b128); stage 1 k-half
// (2 gload_lds); setprio(1); 16 MFMA; setprio(0). NO barrier between read and MFMA
// (per-wave lgkmcnt slip = the m201 overlap mechanism). Counted vmcnt(8) at phases 1,3;
// stages: ph1=A-k1(t+1), ph2=B-k1(t+1), ph3=A-k0(t+2), ph4=B-k0(t+2). Last tile peeled
// with vmcnt(4)/vmcnt(0). R2-proven unit swizzle (0 conflicts).

#define AS1 __attribute__((address_space(1)))
#define AS3 __attribute__((address_space(3)))

__global__ __launch_bounds__(512, 2) void conv_gemm(
    const unsigned short* __restrict__ wa,   // [32][256][2304] bf16
    const unsigned short* __restrict__ xbt,  // [32][3364][256] bf16 (padded NHWC)
    float* __restrict__ out)                 // [32][256][3136]
{
    __shared__ __attribute__((aligned(16))) char lds[131072];

    // XCD swizzle: 416 blocks = 8 XCD * 52; 4 whole batches per XCD
    const int bid = blockIdx.x;
    const int wg  = (bid & 7) * 52 + (bid >> 3);
    const int nt  = wg % 13, b = wg / 13;

    const int t = threadIdx.x;
    const int w = t >> 6, l = t & 63;            // 8 waves
    const int wm = w >> 2, wn = w & 3;           // 2M x 4N, wave tile 128oc x 64px

    const unsigned short* waB = wa + (size_t)b * NOC * KTOT;
    const unsigned short* xbB = xbt + (size_t)b * PPIX * NC;

    // ---- staging sources: chunk c = j*512 + t (j=0,1); row = c>>2, phys = c&3,
    //      stored logical chunk q = (c&3) ^ ((c>>3)&3)  [R2-proven swizzle]
    const unsigned short* pAs[2];
    const unsigned short* pBs[2];
    #pragma unroll
    for (int j = 0; j < 2; ++j) {
        int c = j * 512 + t;
        int row = c >> 2;
        int q = (c & 3) ^ ((c >> 3) & 3);
        pAs[j] = waB + (size_t)row * KTOT + q * 8;
        int pg = nt * 256 + row; if (pg > NPIX - 1) pg = NPIX - 1;
        int py = pg / 56, px = pg - py * 56;
        pBs[j] = xbB + (size_t)((py + 1) * PW + (px + 1)) * NC + q * 8;
    }
    const int t16 = t * 16;

    auto stageA = [&](int kt, int kh) {
        char* dst = lds + (kt & 1) * 65536 + kh * 16384;
        #pragma unroll
        for (int j = 0; j < 2; ++j)
            __builtin_amdgcn_global_load_lds(
                (const AS1 void*)(pAs[j] + kt * 64 + kh * 32),
                (AS3 void*)(dst + j * 8192 + t16), 16, 0, 0);
    };
    auto stageB = [&](int kt, int kh) {
        char* dst = lds + (kt & 1) * 65536 + 32768 + kh * 16384;
        const int s9 = kt >> 2;
        const int dy = (s9 >= 6) ? 2 : ((s9 >= 3) ? 1 : 0);
        const int dx = s9 - dy * 3;
        const int off = ((dy - 1) * PW + (dx - 1)) * NC + (kt & 3) * 64 + kh * 32;
        #pragma unroll
        for (int j = 0; j < 2; ++j)
            __builtin_amdgcn_global_load_lds(
                (const AS1 void*)(pBs[j] + off),
                (AS3 void*)(dst + j * 8192 + t16), 16, 0, 0);
    };

    // ---- read-side lane constants (R2-proven, 0 conflicts) ----
    const int laneRow = (l & 15) * 64;
    const int laneQ   = (((l >> 4) ^ ((l >> 1) & 3)) << 4);

    f32x4 acc[8][4] = {};
    bf16x8 bfr[4];

#define VM8  asm volatile("s_waitcnt vmcnt(8)" ::: "memory")
#define VM4  asm volatile("s_waitcnt vmcnt(4)" ::: "memory")
#define VM0  asm volatile("s_waitcnt vmcnt(0)" ::: "memory")

#define PHASE(MH, KH, DB, STAGE_STMT)                                             \
    do {                                                                          \
        __builtin_amdgcn_s_barrier();                                             \
        __builtin_amdgcn_sched_barrier(0);                                        \
        const char* ab_ = (DB) + (KH) * 16384;                                    \
        bf16x8 af_[4];                                                            \
        _Pragma("unroll")                                                         \
        for (int m = 0; m < 4; ++m)                                               \
            af_[m] = *(const bf16x8*)(ab_ + (wm * 8 + (MH) * 4 + m) * 1024        \
                                      + laneRow + laneQ);                         \
        if ((MH) == 0) {                                                          \
            _Pragma("unroll")                                                     \
            for (int n = 0; n < 4; ++n)                                           \
                bfr[n] = *(const bf16x8*)(ab_ + 32768 + (wn * 4 + n) * 1024       \
                                          + laneRow + laneQ);                     \
        }                                                                         \
        STAGE_STMT;                                                               \
        __builtin_amdgcn_s_setprio(1);                                            \
        _Pragma("unroll")                                                         \
        for (int m = 0; m < 4; ++m)                                               \
            _Pragma("unroll")                                                     \
            for (int n = 0; n < 4; ++n)                                           \
                acc[(MH) * 4 + m][n] = __builtin_amdgcn_mfma_f32_16x16x32_bf16(   \
                    af_[m], bfr[n], acc[(MH) * 4 + m][n], 0, 0, 0);               \
        __builtin_amdgcn_s_setprio(0);                                            \
    } while (0)

    // prologue: tile0 all 4 halves + tile1 k0 halves (12 loads outstanding)
    stageA(0, 0); stageB(0, 0); stageA(0, 1); stageB(0, 1);
    stageA(1, 0); stageB(1, 0);

    for (int tt = 0; tt < 35; ++tt) {
        char* dc = lds + (tt & 1) * 65536;
        VM8; PHASE(0, 0, dc, { stageA(tt + 1, 1); });
             PHASE(1, 0, dc, { stageB(tt + 1, 1); });
        VM8; PHASE(0, 1, dc, { if (tt < 34) stageA(tt + 2, 0); });
             PHASE(1, 1, dc, { if (tt < 34) stageB(tt + 2, 0); });
    }
    {   // tt = 35 (peeled: drain)
        char* dc = lds + 65536;
        VM4; PHASE(0, 0, dc, {});
             PHASE(1, 0, dc, {});
        VM0; PHASE(0, 1, dc, {});
             PHASE(1, 1, dc, {});
    }
#undef PHASE

    // epilogue: D lane map col = l&15 (pixel), row = (l>>4)*4 + r (oc)
    const int ocb = wm * 128 + ((l >> 4) << 2);
    const int pxb = nt * 256 + wn * 64 + (l & 15);
    #pragma unroll
    for (int i = 0; i < 8; ++i) {
        #pragma unroll
        for (int j = 0; j < 4; ++j) {
            int p = pxb + j * 16;
            if (p < NPIX) {
                float* o = out + ((size_t)(b * NOC + ocb + i * 16)) * NPIX + p;
                o[0]        = acc[i][j][0];
                o[NPIX]     = acc[i][j][1];
                o[2 * NPIX] = acc[i][j][2];
                o[3 * NPIX] = acc[i][j][3];
            }
        }
    }
}

extern "C" void kernel_launch(void* const* d_in, const int* in_sizes, int n_in,
                              void* d_out, int out_size, void* d_ws, size_t ws_size,
                              hipStream_t stream) {
    (void)in_sizes; (void)n_in; (void)out_size; (void)ws_size;
    const float* x   = (const float*)d_in[0];
    const float* rw  = (const float*)d_in[1];
    const float* rb  = (const float*)d_in[2];
    const float* f1w = (const float*)d_in[3];
    const float* f2w = (const float*)d_in[4];
    const float* f2b = (const float*)d_in[5];
    float* out = (float*)d_out;

    char* wsb = (char*)d_ws;
    unsigned short* xbt = (unsigned short*)wsb;
    unsigned short* wa  = (unsigned short*)(wsb + XBT_BYTES);
    float* gap = (float*)(wsb + XBT_BYTES + WA_BYTES);
    float* a2  = (float*)(wsb + XBT_BYTES + WA_BYTES + (size_t)NB * NC * 4);

    hipMemsetAsync(gap, 0, (size_t)NB * NC * 4, stream);
    halo_kernel<<<dim3(32), 256, 0, stream>>>(xbt);
    xpose_kernel<<<dim3(56, 32), 256, 0, stream>>>(x, xbt, gap);
    se_kernel<<<dim3(1), 512, 0, stream>>>(gap, rw, rb, f1w, a2);
    wk_kernel<<<dim3(256), 256, 0, stream>>>(a2, f2w, f2b, wa);
    conv_gemm<<<dim3(416), 512, 0, stream>>>(wa, xbt, out);
}

// Round 10
// 186.058 us; speedup vs baseline: 1.4993x; 1.1112x over previous
//
#include <hip/hip_runtime.h>
#include <hip/hip_bf16.h>
#include <stdint.h>

// ---------------- problem constants ----------------
#define NB   32
#define NC   256
#define NOC  256
#define HWD  56
#define NPIX 3136      // 56*56 = 14 * 224 exactly
#define PW   58        // padded row width
#define PPIX 3364      // 58*58
#define KTOT 2304      // 9 * 256
#define MOD  512       // fc1 out channels
#define GAPD 16

// workspace layout (bytes)
#define XBT_BYTES ((size_t)NB * PPIX * NC * 2)            // 55,115,776
#define WA_BYTES  ((size_t)NB * NOC * KTOT * 2)           // 37,748,736

typedef __bf16 bf16x8 __attribute__((ext_vector_type(8)));
typedef float  f32x4  __attribute__((ext_vector_type(4)));
typedef unsigned short u16x8 __attribute__((ext_vector_type(8)));

__device__ __forceinline__ unsigned short f2bf(float f) {
    union { float f; unsigned int u; } v; v.f = f;
    unsigned int u = v.u;
    return (unsigned short)((u + 0x7FFFu + ((u >> 16) & 1u)) >> 16);
}

// ---------------- P1: per-batch conv weights, SE fused in; one block per oc ----------------
__global__ void wk_kernel(const float* __restrict__ gap,
                          const float* __restrict__ rw, const float* __restrict__ rb,
                          const float* __restrict__ f1w,
                          const float* __restrict__ f2w, const float* __restrict__ f2b,
                          unsigned short* __restrict__ wa) {
    __shared__ float sgap[NB * 257];    // stride 257: bank-spread
    __shared__ float srw[GAPD * 257];
    __shared__ float ssg[NB * GAPD];
    __shared__ float sa[2 * NB];
    __shared__ float sw[KTOT];
    __shared__ float sbv[KTOT];
    int oc = blockIdx.x, c = threadIdx.x;
    // stage gap (32x256 = 8192) and rw (16x256 = 4096), padded stride
    #pragma unroll
    for (int i = 0; i < 32; ++i) {                 // FIX (R9 bug): was i<8
        int idx = i * 256 + c;                     // 0..8191
        sgap[(idx >> 8) * 257 + (idx & 255)] = gap[idx];
    }
    #pragma unroll
    for (int i = 0; i < 16; ++i) {                 // FIX (R9 bug): was i<4
        int idx = i * 256 + c;                     // 0..4095
        srw[(idx >> 8) * 257 + (idx & 255)] = rw[idx];
    }
    // stage this oc's fc2 row
    const float4* wsrc = (const float4*)(f2w + (size_t)oc * KTOT);
    const float4* bsrc = (const float4*)(f2b + (size_t)oc * KTOT);
    #pragma unroll
    for (int i = 0; i < 3; ++i) {
        int idx = i * 256 + c;
        if (idx < 576) {
            ((float4*)sw)[idx] = wsrc[idx];
            ((float4*)sbv)[idx] = bsrc[idx];
        }
    }
    __syncthreads();
    // sg[b][tt] = rb[tt] + gap[b,:] . rw[tt,:]   (512 pairs, 2 per thread)
    #pragma unroll
    for (int e = 0; e < 2; ++e) {
        int pair = c * 2 + e;
        int b = pair >> 4, tt = pair & 15;
        float s = rb[tt];
        for (int k = 0; k < NC; ++k) s += sgap[b * 257 + k] * srw[tt * 257 + k];
        ssg[b * GAPD + tt] = s;
    }
    __syncthreads();
    // a(b, 2oc+e) for all 32 b x 2 e: threads c<64
    if (c < 64) {
        int b = c >> 1, e = c & 1;
        float s = 0.f;
        #pragma unroll
        for (int tt = 0; tt < GAPD; ++tt)
            s += ssg[b * GAPD + tt] * f1w[(2 * oc + e) * GAPD + tt];
        sa[c] = 1.0f / (1.0f + __expf(-s));
    }
    __syncthreads();
    float w9[9], b9[9];
    #pragma unroll
    for (int s = 0; s < 9; ++s) { w9[s] = sw[c * 9 + s]; b9[s] = sbv[c * 9 + s]; }
    for (int b = 0; b < NB; ++b) {
        float a0 = sa[2 * b], a1 = sa[2 * b + 1];
        unsigned short* dst = wa + (size_t)(b * NOC + oc) * KTOT;
        #pragma unroll
        for (int s = 0; s < 9; ++s) {
            float a = ((c * 9 + s) >= 1152) ? a1 : a0;
            dst[s * NC + c] = f2bf(a * w9[s] + b9[s]);
        }
    }
}

// ---------------- P2: zero xbt halo + zero gap ----------------
__global__ void halo_kernel(unsigned short* __restrict__ xbt, float* __restrict__ gap) {
    int b = blockIdx.x, t = threadIdx.x;
    gap[b * NC + t] = 0.f;
    unsigned short* xb = xbt + (size_t)b * PPIX * NC;
    u16x8 z = {};
    for (int i = t; i < 3712; i += 256) {
        int r = (i >= 1856) ? 1 : 0;
        int c = i - r * 1856;
        int pix = r * (57 * 58) + (c >> 5);
        *(u16x8*)(xb + (size_t)pix * NC + (c & 31) * 8) = z;
    }
    for (int i = t; i < 3584; i += 256) {
        int row = 1 + (i >> 6);
        int side = (i >> 5) & 1;
        int pix = row * PW + side * 57;
        *(u16x8*)(xb + (size_t)pix * NC + (i & 31) * 8) = z;
    }
}

// ---------------- P3: x -> bf16 NHWC with halo, shuffle-reduced GAP ----------------
#define TSTR 59
__global__ void xpose_kernel(const float* __restrict__ x, unsigned short* __restrict__ xbt,
                             float* __restrict__ gap) {
    __shared__ unsigned short tile[NC * TSTR];
    int py = blockIdx.x, b = blockIdx.y, t = threadIdx.x;
    int wv = t >> 6, l = t & 63;
    const float* xs = x + (size_t)b * NC * NPIX + py * HWD;
    int q = l & 15;
    int rb4 = l >> 4;
    #pragma unroll
    for (int it = 0; it < 16; ++it) {
        int c = wv * 64 + it * 4 + rb4;
        float4 v = {0.f, 0.f, 0.f, 0.f};
        if (q < 14) {
            v = *(const float4*)(xs + (size_t)c * NPIX + q * 4);
            unsigned short* tr = tile + c * TSTR + q * 4;
            tr[0] = f2bf(v.x); tr[1] = f2bf(v.y); tr[2] = f2bf(v.z); tr[3] = f2bf(v.w);
        }
        // fused GAP: reduce row-sum across the 16 q-lanes (bits 0-3 of lane id)
        float s4 = v.x + v.y + v.z + v.w;
        s4 += __shfl_xor(s4, 1);
        s4 += __shfl_xor(s4, 2);
        s4 += __shfl_xor(s4, 4);
        s4 += __shfl_xor(s4, 8);
        if (q == 0) atomicAdd(&gap[b * NC + c], s4 * (1.0f / NPIX));
    }
    __syncthreads();
    int cch = t & 31, pg = t >> 5;
    for (int i = 0; i < 7; ++i) {
        int px = pg * 7 + i;
        u16x8 v;
        #pragma unroll
        for (int j = 0; j < 8; ++j) v[j] = tile[(cch * 8 + j) * TSTR + px];
        *(u16x8*)(xbt + ((size_t)b * PPIX + (size_t)(1 + py) * PW + 1 + px) * NC + cch * 8) = v;
    }
}

// ---------------- main GEMM: 256oc x 224px tile, 8 waves (4M x 2N, wave 64x112) ----------------
// 3136 = 14*224 -> no pixel guards; grid 448 = 8 XCD * 56 -> round packing 87.5%.
// K = 2304 = 72 steps of BK=32. Slice = A[256][32] (16KB) + B[224+pad32][32] (16KB) = 32KB;
// ring-4 = 128KB. R2-proven structure: issue(p+2) -> vmcnt(8)+barrier -> compute(p).
// R2-proven unit swizzle (1KB unit = 16 rows x 4 chunks of 16B; 0 conflicts).
#define SLICE 32768
#define BOFS  16384

#define PWAIT(N) do { asm volatile("s_waitcnt vmcnt(" #N ")" ::: "memory"); \
    __builtin_amdgcn_s_barrier(); __builtin_amdgcn_sched_barrier(0); } while (0)

__global__ __launch_bounds__(512, 2) void conv_gemm(
    const unsigned short* __restrict__ wa,   // [32][256][2304] bf16
    const unsigned short* __restrict__ xbt,  // [32][3364][256] bf16 (padded NHWC)
    float* __restrict__ out)                 // [32][256][3136]
{
    __shared__ __attribute__((aligned(16))) char lds[4 * SLICE];  // 128 KB

    // XCD swizzle: 448 blocks = 8 XCD * 56; 4 whole batches per XCD
    const int bid = blockIdx.x;
    const int wg  = (bid & 7) * 56 + (bid >> 3);
    const int b   = wg / 14, nt = wg % 14;

    const int t = threadIdx.x;
    const int w = t >> 6, l = t & 63;            // 8 waves
    const int wm = w >> 1, wn = w & 1;           // 4M x 2N, wave tile 64oc x 112px

    const unsigned short* waB = wa + (size_t)b * NOC * KTOT;
    const unsigned short* xbB = xbt + (size_t)b * PPIX * NC;

    // ---- staging sources (pre-swizzled, R2 mapping): chunk c = j*512 + t ----
    // unit u = c>>6, in-unit lane cc = c&63: row = u*16 + (cc>>2), phys = cc&3,
    // stored logical chunk qv = (cc&3) ^ ((cc>>3)&3)
    const unsigned short* srcA[2];
    const unsigned short* srcB[2];
    #pragma unroll
    for (int j = 0; j < 2; ++j) {
        int cix = j * 512 + t;
        int cc  = cix & 63;
        int row = (cix >> 6) * 16 + (cc >> 2);
        int qv  = (cc & 3) ^ ((cc >> 3) & 3);
        srcA[j] = waB + (size_t)row * KTOT + qv * 8;
        int pg = nt * 224 + row; if (pg > NPIX - 1) pg = NPIX - 1;  // pad units only
        int py = pg / 56, px = pg - py * 56;
        srcB[j] = xbB + (size_t)((py + 1) * PW + (px + 1)) * NC + qv * 8;
    }
    const int t16 = t * 16;

    auto issue = [&](int tp, int slot) {
        char* sb = lds + slot * SLICE;
        const int koff = tp * 32;                       // A: k = s*256+c linear
        const int s9 = tp >> 3;
        const int dy = (s9 >= 6) ? 2 : ((s9 >= 3) ? 1 : 0);
        const int dx = s9 - dy * 3;
        const int bsh = ((dy - 1) * PW + (dx - 1)) * NC + (tp & 7) * 32;
        #pragma unroll
        for (int j = 0; j < 2; ++j)
            __builtin_amdgcn_global_load_lds(
                (const __attribute__((address_space(1))) void*)(srcA[j] + koff),
                (__attribute__((address_space(3))) void*)(sb + j * 8192 + t16), 16, 0, 0);
        #pragma unroll
        for (int j = 0; j < 2; ++j)
            __builtin_amdgcn_global_load_lds(
                (const __attribute__((address_space(1))) void*)(srcB[j] + bsh),
                (__attribute__((address_space(3))) void*)(sb + BOFS + j * 8192 + t16), 16, 0, 0);
    };

    // ---- read-side lane constants (R2-proven, 0 conflicts) ----
    const int physq16 = (((l >> 4) ^ ((l >> 1) & 3)) << 4);
    const int arow = (l & 15) << 6;

    f32x4 acc[4][7] = {};

    auto compute = [&](int slot) {
        const char* sb = lds + slot * SLICE;
        bf16x8 af[4], bfr[7];
        #pragma unroll
        for (int m = 0; m < 4; ++m)
            af[m] = *(const bf16x8*)(sb + (wm * 4 + m) * 1024 + arow + physq16);
        #pragma unroll
        for (int j = 0; j < 7; ++j)
            bfr[j] = *(const bf16x8*)(sb + BOFS + (wn * 7 + j) * 1024 + arow + physq16);
        __builtin_amdgcn_s_setprio(1);
        #pragma unroll
        for (int m = 0; m < 4; ++m)
            #pragma unroll
            for (int j = 0; j < 7; ++j)
                acc[m][j] = __builtin_amdgcn_mfma_f32_16x16x32_bf16(af[m], bfr[j], acc[m][j], 0, 0, 0);
        __builtin_amdgcn_s_setprio(0);
    };

    issue(0, 0); issue(1, 1);

    #pragma unroll 4
    for (int p = 0; p < 70; ++p) {
        issue(p + 2, (p + 2) & 3);
        PWAIT(8);
        compute(p & 3);
    }
    PWAIT(4); compute(70 & 3);
    PWAIT(0); compute(71 & 3);

    // epilogue: D lane map col = l&15 (pixel), row = (l>>4)*4 + r (oc)
    const int ocb = wm * 64 + ((l >> 4) << 2);
    const int pxb = nt * 224 + wn * 112 + (l & 15);
    #pragma unroll
    for (int i = 0; i < 4; ++i) {
        #pragma unroll
        for (int j = 0; j < 7; ++j) {
            float* o = out + ((size_t)(b * NOC + ocb + i * 16)) * NPIX + pxb + j * 16;
            o[0]        = acc[i][j][0];
            o[NPIX]     = acc[i][j][1];
            o[2 * NPIX] = acc[i][j][2];
            o[3 * NPIX] = acc[i][j][3];
        }
    }
}

extern "C" void kernel_launch(void* const* d_in, const int* in_sizes, int n_in,
                              void* d_out, int out_size, void* d_ws, size_t ws_size,
                              hipStream_t stream) {
    (void)in_sizes; (void)n_in; (void)out_size; (void)ws_size;
    const float* x   = (const float*)d_in[0];
    const float* rw  = (const float*)d_in[1];
    const float* rb  = (const float*)d_in[2];
    const float* f1w = (const float*)d_in[3];
    const float* f2w = (const float*)d_in[4];
    const float* f2b = (const float*)d_in[5];
    float* out = (float*)d_out;

    char* wsb = (char*)d_ws;
    unsigned short* xbt = (unsigned short*)wsb;
    unsigned short* wa  = (unsigned short*)(wsb + XBT_BYTES);
    float* gap = (float*)(wsb + XBT_BYTES + WA_BYTES);

    halo_kernel<<<dim3(32), 256, 0, stream>>>(xbt, gap);
    xpose_kernel<<<dim3(56, 32), 256, 0, stream>>>(x, xbt, gap);
    wk_kernel<<<dim3(256), 256, 0, stream>>>(gap, rw, rb, f1w, f2w, f2b, wa);
    conv_gemm<<<dim3(448), 512, 0, stream>>>(wa, xbt, out);
}